// Round 5
// baseline (246.203 us; speedup 1.0000x reference)
//
#include <hip/hip_runtime.h>

// Shift op: out[n, c*9 + s, h, w] = x_pad[n, c, h + s/3, w + s%3], pad=1.
// x: (32, 64, 56, 56) fp32 -> out: (32, 576, 56, 56).
//
// R4->R5: one block per (n,c) input plane (2048 blocks x 256 thr).
// Plane (12.5 KB) staged once into a zero-padded LDS tile (58 rows x 68
// cols, data at [h+1][w+4]); all 9 shifted output planes (110 KB) are then
// written as perfectly linear consecutive-lane float4 streams. Input is
// fetched exactly once per plane; boundary handling is branch-free via the
// pre-zeroed LDS border.

#define N_ 32
#define C_ 64
#define H_ 56
#define W_ 56
#define W4 14                      // float4s per row
#define PLANE (H_ * W_)            // 3136 floats per (n,c) plane
#define PLANE4 (H_ * W4)           // 784 float4s per plane
#define LROW 68                    // LDS row stride (floats)
#define LROWS 58                   // padded rows
#define LSIZE (LROWS * LROW)       // 3944 floats = 15.8 KB

typedef float f4 __attribute__((ext_vector_type(4)));

__global__ __launch_bounds__(256) void shift_kernel(const float* __restrict__ x,
                                                    f4* __restrict__ out) {
    __shared__ float lds[LSIZE];
    const int tid = threadIdx.x;
    const int nc  = blockIdx.x;           // 0 .. N_*C_-1

    // 1) zero the whole tile (border must be 0)
    for (int i = tid; i < LSIZE; i += 256) lds[i] = 0.f;
    __syncthreads();

    // 2) stage the plane: interior at lds[(h+1)*LROW + 4 + w]
    const f4* src = (const f4*)(x + (long)nc * PLANE);
    for (int i = tid; i < PLANE4; i += 256) {
        int h  = i / W4;
        int w4 = i % W4;
        f4 v = src[i];
        *(f4*)&lds[(h + 1) * LROW + 4 + 4 * w4] = v;   // 16B-aligned (LROW%4==0)
    }
    __syncthreads();

    // 3) emit 9 shifted planes, fully linear stores
    f4* ob = out + (long)nc * 9 * PLANE4;
#pragma unroll
    for (int s = 0; s < 9; ++s) {
        const int dyi = s / 3;      // 0..2  (lds row = h + dyi)
        const int dxi = s % 3;      // 0..2  (lds col = 3 + w + dxi)
        f4* op = ob + (long)s * PLANE4;
        for (int i = tid; i < PLANE4; i += 256) {
            int h  = i / W4;
            int w0 = 4 * (i % W4);
            const float* p = &lds[(h + dyi) * LROW + 3 + dxi + w0];
            f4 v = { p[0], p[1], p[2], p[3] };
            __builtin_nontemporal_store(v, op + i);
        }
    }
}

extern "C" void kernel_launch(void* const* d_in, const int* in_sizes, int n_in,
                              void* d_out, int out_size, void* d_ws, size_t ws_size,
                              hipStream_t stream) {
    const float* x = (const float*)d_in[0];
    f4* out = (f4*)d_out;
    shift_kernel<<<N_ * C_, 256, 0, stream>>>(x, out);
}